// Round 2
// baseline (911.592 us; speedup 1.0000x reference)
//
#include <hip/hip_runtime.h>
#include <hip/hip_bf16.h>

typedef __hip_bfloat16 bf16;

#define N_NODES 50000
#define N_EDGES 300000
#define F_IN    128
#define HD      256
#define N_C     3
#define N_G     64
#define NEG_SLOPE 0.2f

__device__ __forceinline__ float b2f(unsigned short u) {
    return __uint_as_float(((unsigned int)u) << 16);
}

// ---------------- init: deg=1 (self loop), gsum=0 ----------------
__global__ void init_kernel(int* deg, float* gsum, int n) {
    int i = blockIdx.x * blockDim.x + threadIdx.x;
    if (i < n) deg[i] = 1;
    if (i < N_G * N_C) gsum[i] = 0.f;
}

// ---------------- count in-degrees ----------------
__global__ void count_kernel(const int* __restrict__ ei, int* deg, int e) {
    int i = blockIdx.x * blockDim.x + threadIdx.x;
    if (i < e) atomicAdd(&deg[ei[e + i]], 1);
}

// ---------------- exclusive scan (single block, 1024 thr) ----------------
__global__ __launch_bounds__(1024) void scan_kernel(const int* __restrict__ deg,
                                                    int* __restrict__ offs, int n) {
    __shared__ int wsum[16];
    __shared__ int blocktot;
    int tid = threadIdx.x, lane = tid & 63, wid = tid >> 6;
    int carry = 0;
    for (int base = 0; base < n; base += 1024) {
        int i = base + tid;
        int v = (i < n) ? deg[i] : 0;
        int x = v;
        #pragma unroll
        for (int o = 1; o < 64; o <<= 1) {
            int y = __shfl_up(x, o, 64);
            if (lane >= o) x += y;
        }
        if (lane == 63) wsum[wid] = x;
        __syncthreads();
        if (tid == 0) {
            int run = 0;
            for (int w = 0; w < 16; w++) { int t = wsum[w]; wsum[w] = run; run += t; }
            blocktot = run;
        }
        __syncthreads();
        if (i < n) offs[i] = carry + wsum[wid] + (x - v);
        carry += blocktot;
        __syncthreads();
    }
    if (tid == 0) offs[n] = carry;
}

// ---------------- place self-loops, set cursors ----------------
__global__ void selfloop_kernel(const int* __restrict__ offs, int* __restrict__ ssrc,
                                int* __restrict__ cursor, int n) {
    int i = blockIdx.x * blockDim.x + threadIdx.x;
    if (i < n) {
        int o = offs[i];
        ssrc[o] = i;
        cursor[i] = o + 1;
    }
}

// ---------------- scatter edges into CSR by target ----------------
__global__ void scatter_kernel(const int* __restrict__ ei, int* cursor,
                               int* __restrict__ ssrc, int e) {
    int i = blockIdx.x * blockDim.x + threadIdx.x;
    if (i < e) {
        int s = ei[i];
        int t = ei[e + i];
        int p = atomicAdd(&cursor[t], 1);
        ssrc[p] = s;
    }
}

// ---------------- xw = x @ W  (8 nodes per 256-thread block), fp32 in, bf16 out
__global__ __launch_bounds__(256) void xw_kernel(const float* __restrict__ x,
                                                 const float* __restrict__ W,
                                                 bf16* __restrict__ xw) {
    __shared__ float xs[8 * F_IN];
    int t = threadIdx.x;           // == output column hd (0..255)
    int nb = blockIdx.x * 8;
    // load 8 node rows (8*128 fp32) into LDS; 4 per thread, contiguous
    ((float4*)xs)[t] = ((const float4*)(x + (size_t)nb * F_IN))[t];
    __syncthreads();
    float acc[8] = {0.f, 0.f, 0.f, 0.f, 0.f, 0.f, 0.f, 0.f};
    for (int f = 0; f < F_IN; f++) {
        float w = W[f * HD + t];
        #pragma unroll
        for (int k = 0; k < 8; k++) acc[k] += xs[k * F_IN + f] * w;
    }
    bf16* outp = xw + (size_t)nb * HD + t;
    #pragma unroll
    for (int k = 0; k < 8; k++) outp[k * HD] = __float2bfloat16(acc[k]);
}

// ---------------- per-node attention coefficients a_s, a_d ----------------
// asd layout: [n][4] = {as_h0, as_h1, ad_h0, ad_h1}
__global__ __launch_bounds__(256) void asd_kernel(const bf16* __restrict__ xw,
                                                  const float* __restrict__ att_src,
                                                  const float* __restrict__ att_dst,
                                                  float* __restrict__ asd, int n) {
    int wid = threadIdx.x >> 6, lane = threadIdx.x & 63;
    int node = blockIdx.x * 4 + wid;
    if (node >= n) return;
    ushort4 v = ((const ushort4*)(xw + (size_t)node * HD))[lane];
    float4 s = ((const float4*)att_src)[lane];
    float4 d = ((const float4*)att_dst)[lane];
    float ps = b2f(v.x) * s.x + b2f(v.y) * s.y + b2f(v.z) * s.z + b2f(v.w) * s.w;
    float pd = b2f(v.x) * d.x + b2f(v.y) * d.y + b2f(v.z) * d.z + b2f(v.w) * d.w;
    // reduce within each 32-lane half (= one head each)
    #pragma unroll
    for (int o = 16; o > 0; o >>= 1) {
        ps += __shfl_xor(ps, o, 64);
        pd += __shfl_xor(pd, o, 64);
    }
    if (lane == 0)  { asd[node * 4 + 0] = ps; asd[node * 4 + 2] = pd; }
    if (lane == 32) { asd[node * 4 + 1] = ps; asd[node * 4 + 3] = pd; }
}

// ---------------- main: softmax-aggregate + bias/relu + FC + node log_softmax
//                  + atomic pool into graph sums ----------------
__global__ __launch_bounds__(256) void main_kernel(const bf16* __restrict__ xw,
                                                   const float* __restrict__ asd,
                                                   const int* __restrict__ offs,
                                                   const int* __restrict__ ssrc,
                                                   const int* __restrict__ batch,
                                                   const float* __restrict__ bias,
                                                   const float* __restrict__ fcw,
                                                   const float* __restrict__ fcb,
                                                   float* __restrict__ gsum, int n) {
    int wid = threadIdx.x >> 6, lane = threadIdx.x & 63;
    int node = blockIdx.x * 4 + wid;
    if (node >= n) return;
    float4 my = ((const float4*)asd)[node];
    float ad0 = my.z, ad1 = my.w;
    int beg = offs[node], end = offs[node + 1];

    // pass 1: online softmax stats per head
    float m0 = -1e30f, m1 = -1e30f, s0 = 0.f, s1 = 0.f;
    for (int e = beg; e < end; e++) {
        int s = ssrc[e];
        float4 sa = ((const float4*)asd)[s];
        float e0 = sa.x + ad0; e0 = (e0 > 0.f) ? e0 : NEG_SLOPE * e0;
        float e1 = sa.y + ad1; e1 = (e1 > 0.f) ? e1 : NEG_SLOPE * e1;
        float nm0 = fmaxf(m0, e0);
        s0 = s0 * __expf(m0 - nm0) + __expf(e0 - nm0); m0 = nm0;
        float nm1 = fmaxf(m1, e1);
        s1 = s1 * __expf(m1 - nm1) + __expf(e1 - nm1); m1 = nm1;
    }
    float inv0 = 1.f / s0, inv1 = 1.f / s1;

    // pass 2: weighted gather. lane covers hd = lane*4 .. lane*4+3
    float a0 = 0.f, a1 = 0.f, a2 = 0.f, a3 = 0.f;
    for (int e = beg; e < end; e++) {
        int s = ssrc[e];
        float4 sa = ((const float4*)asd)[s];
        float e0 = sa.x + ad0; e0 = (e0 > 0.f) ? e0 : NEG_SLOPE * e0;
        float e1 = sa.y + ad1; e1 = (e1 > 0.f) ? e1 : NEG_SLOPE * e1;
        float al0 = __expf(e0 - m0) * inv0;
        float al1 = __expf(e1 - m1) * inv1;
        float al = (lane < 32) ? al0 : al1;
        ushort4 v = ((const ushort4*)(xw + (size_t)s * HD))[lane];
        a0 += al * b2f(v.x); a1 += al * b2f(v.y);
        a2 += al * b2f(v.z); a3 += al * b2f(v.w);
    }

    // epilogue: + bias, relu
    float4 bv = ((const float4*)bias)[lane];
    float z0 = fmaxf(a0 + bv.x, 0.f);
    float z1 = fmaxf(a1 + bv.y, 0.f);
    float z2 = fmaxf(a2 + bv.z, 0.f);
    float z3 = fmaxf(a3 + bv.w, 0.f);

    // FC 256 -> 3 : per-lane partial then wave reduce
    int hd = lane * 4;
    float l0 = z0 * fcw[(hd + 0) * 3 + 0] + z1 * fcw[(hd + 1) * 3 + 0]
             + z2 * fcw[(hd + 2) * 3 + 0] + z3 * fcw[(hd + 3) * 3 + 0];
    float l1 = z0 * fcw[(hd + 0) * 3 + 1] + z1 * fcw[(hd + 1) * 3 + 1]
             + z2 * fcw[(hd + 2) * 3 + 1] + z3 * fcw[(hd + 3) * 3 + 1];
    float l2 = z0 * fcw[(hd + 0) * 3 + 2] + z1 * fcw[(hd + 1) * 3 + 2]
             + z2 * fcw[(hd + 2) * 3 + 2] + z3 * fcw[(hd + 3) * 3 + 2];
    #pragma unroll
    for (int o = 32; o > 0; o >>= 1) {
        l0 += __shfl_xor(l0, o, 64);
        l1 += __shfl_xor(l1, o, 64);
        l2 += __shfl_xor(l2, o, 64);
    }
    if (lane == 0) {
        l0 += fcb[0]; l1 += fcb[1]; l2 += fcb[2];
        float m = fmaxf(l0, fmaxf(l1, l2));
        float lse = m + __logf(__expf(l0 - m) + __expf(l1 - m) + __expf(l2 - m));
        int b = batch[node];
        atomicAdd(&gsum[b * 3 + 0], l0 - lse);
        atomicAdd(&gsum[b * 3 + 1], l1 - lse);
        atomicAdd(&gsum[b * 3 + 2], l2 - lse);
    }
}

// ---------------- final: scale by a, log_softmax over classes ----------------
__global__ void final_kernel(const float* __restrict__ gsum, const float* __restrict__ a,
                             float* __restrict__ out) {
    int g = threadIdx.x;
    if (g < N_G) {
        float av = a[0];
        float v0 = gsum[g * 3 + 0] * av;
        float v1 = gsum[g * 3 + 1] * av;
        float v2 = gsum[g * 3 + 2] * av;
        float m = fmaxf(v0, fmaxf(v1, v2));
        float lse = m + __logf(__expf(v0 - m) + __expf(v1 - m) + __expf(v2 - m));
        out[g * 3 + 0] = v0 - lse;
        out[g * 3 + 1] = v1 - lse;
        out[g * 3 + 2] = v2 - lse;
    }
}

extern "C" void kernel_launch(void* const* d_in, const int* in_sizes, int n_in,
                              void* d_out, int out_size, void* d_ws, size_t ws_size,
                              hipStream_t stream) {
    const float* x       = (const float*)d_in[0];
    const int*   ei      = (const int*)d_in[1];
    const int*   batch   = (const int*)d_in[2];
    const float* W       = (const float*)d_in[3];
    const float* att_src = (const float*)d_in[4];
    const float* att_dst = (const float*)d_in[5];
    const float* bias    = (const float*)d_in[6];
    const float* fcw     = (const float*)d_in[7];
    const float* fcb     = (const float*)d_in[8];
    const float* a_scale = (const float*)d_in[9];
    float* out = (float*)d_out;

    const int n = in_sizes[2];       // N nodes (50000)
    const int e = in_sizes[1] / 2;   // E edges (300000)

    char* ws = (char*)d_ws;
    bf16*  xw     = (bf16*)ws;                        // N*256 bf16 = 25.6 MB
    float* asd    = (float*)(ws + 25600000);          // N*4  fp32 = 800 KB
    int*   deg    = (int*)(ws + 26400000);            // N ints (counts, then cursor)
    int*   offs   = (int*)(ws + 26600000);            // N+1 ints
    int*   ssrc   = (int*)(ws + 26800256);            // (E+N) ints
    float* gsum   = (float*)(ws + 28200256);          // 64*3 fp32

    int nb256 = (n + 255) / 256;
    int eb256 = (e + 255) / 256;

    hipLaunchKernelGGL(init_kernel,     dim3(nb256), dim3(256), 0, stream, deg, gsum, n);
    hipLaunchKernelGGL(count_kernel,    dim3(eb256), dim3(256), 0, stream, ei, deg, e);
    hipLaunchKernelGGL(scan_kernel,     dim3(1), dim3(1024), 0, stream, deg, offs, n);
    hipLaunchKernelGGL(selfloop_kernel, dim3(nb256), dim3(256), 0, stream, offs, ssrc, deg, n);
    hipLaunchKernelGGL(scatter_kernel,  dim3(eb256), dim3(256), 0, stream, ei, deg, ssrc, e);
    hipLaunchKernelGGL(xw_kernel,       dim3(n / 8), dim3(256), 0, stream, x, W, xw);
    hipLaunchKernelGGL(asd_kernel,      dim3((n + 3) / 4), dim3(256), 0, stream, xw, att_src, att_dst, asd, n);
    hipLaunchKernelGGL(main_kernel,     dim3((n + 3) / 4), dim3(256), 0, stream,
                       xw, asd, offs, ssrc, batch, bias, fcw, fcb, gsum, n);
    hipLaunchKernelGGL(final_kernel,    dim3(1), dim3(64), 0, stream, gsum, a_scale, out);
}

// Round 3
// 829.265 us; speedup vs baseline: 1.0993x; 1.0993x over previous
//
#include <hip/hip_runtime.h>
#include <hip/hip_bf16.h>

typedef __hip_bfloat16 bf16;

#define N_NODES 50000
#define N_EDGES 300000
#define F_IN    128
#define HD      256
#define N_C     3
#define N_G     64
#define NEG_SLOPE 0.2f

__device__ __forceinline__ float b2f(unsigned short u) {
    return __uint_as_float(((unsigned int)u) << 16);
}

// ---------------- init: deg=1 (self loop), gsum=0 ----------------
__global__ void init_kernel(int* deg, float* gsum, int n) {
    int i = blockIdx.x * blockDim.x + threadIdx.x;
    if (i < n) deg[i] = 1;
    if (i < N_G * N_C) gsum[i] = 0.f;
}

// ---------------- count in-degrees ----------------
__global__ void count_kernel(const int* __restrict__ ei, int* deg, int e) {
    int i = blockIdx.x * blockDim.x + threadIdx.x;
    if (i < e) atomicAdd(&deg[ei[e + i]], 1);
}

// ---------------- exclusive scan (single block, 1024 thr) ----------------
__global__ __launch_bounds__(1024) void scan_kernel(const int* __restrict__ deg,
                                                    int* __restrict__ offs, int n) {
    __shared__ int wsum[16];
    __shared__ int blocktot;
    int tid = threadIdx.x, lane = tid & 63, wid = tid >> 6;
    int carry = 0;
    for (int base = 0; base < n; base += 1024) {
        int i = base + tid;
        int v = (i < n) ? deg[i] : 0;
        int x = v;
        #pragma unroll
        for (int o = 1; o < 64; o <<= 1) {
            int y = __shfl_up(x, o, 64);
            if (lane >= o) x += y;
        }
        if (lane == 63) wsum[wid] = x;
        __syncthreads();
        if (tid == 0) {
            int run = 0;
            for (int w = 0; w < 16; w++) { int t = wsum[w]; wsum[w] = run; run += t; }
            blocktot = run;
        }
        __syncthreads();
        if (i < n) offs[i] = carry + wsum[wid] + (x - v);
        carry += blocktot;
        __syncthreads();
    }
    if (tid == 0) offs[n] = carry;
}

// ---------------- place self-loops, set cursors ----------------
__global__ void selfloop_kernel(const int* __restrict__ offs, int* __restrict__ ssrc,
                                int* __restrict__ cursor, int n) {
    int i = blockIdx.x * blockDim.x + threadIdx.x;
    if (i < n) {
        int o = offs[i];
        ssrc[o] = i;
        cursor[i] = o + 1;
    }
}

// ---------------- scatter edges into CSR by target ----------------
__global__ void scatter_kernel(const int* __restrict__ ei, int* cursor,
                               int* __restrict__ ssrc, int e) {
    int i = blockIdx.x * blockDim.x + threadIdx.x;
    if (i < e) {
        int s = ei[i];
        int t = ei[e + i];
        int p = atomicAdd(&cursor[t], 1);
        ssrc[p] = s;
    }
}

// ---------------- xw = x @ W  (8 nodes per 256-thread block), fp32 in, bf16 out
__global__ __launch_bounds__(256) void xw_kernel(const float* __restrict__ x,
                                                 const float* __restrict__ W,
                                                 bf16* __restrict__ xw) {
    __shared__ float xs[8 * F_IN];
    int t = threadIdx.x;           // == output column hd (0..255)
    int nb = blockIdx.x * 8;
    ((float4*)xs)[t] = ((const float4*)(x + (size_t)nb * F_IN))[t];
    __syncthreads();
    float acc[8] = {0.f, 0.f, 0.f, 0.f, 0.f, 0.f, 0.f, 0.f};
    for (int f = 0; f < F_IN; f++) {
        float w = W[f * HD + t];
        #pragma unroll
        for (int k = 0; k < 8; k++) acc[k] += xs[k * F_IN + f] * w;
    }
    bf16* outp = xw + (size_t)nb * HD + t;
    #pragma unroll
    for (int k = 0; k < 8; k++) outp[k * HD] = __float2bfloat16(acc[k]);
}

// ---------------- per-node attention coefficients a_s, a_d ----------------
// asd layout: [n][4] = {as_h0, as_h1, ad_h0, ad_h1}
__global__ __launch_bounds__(256) void asd_kernel(const bf16* __restrict__ xw,
                                                  const float* __restrict__ att_src,
                                                  const float* __restrict__ att_dst,
                                                  float* __restrict__ asd, int n) {
    int wid = threadIdx.x >> 6, lane = threadIdx.x & 63;
    int node = blockIdx.x * 4 + wid;
    if (node >= n) return;
    ushort4 v = ((const ushort4*)(xw + (size_t)node * HD))[lane];
    float4 s = ((const float4*)att_src)[lane];
    float4 d = ((const float4*)att_dst)[lane];
    float ps = b2f(v.x) * s.x + b2f(v.y) * s.y + b2f(v.z) * s.z + b2f(v.w) * s.w;
    float pd = b2f(v.x) * d.x + b2f(v.y) * d.y + b2f(v.z) * d.z + b2f(v.w) * d.w;
    #pragma unroll
    for (int o = 16; o > 0; o >>= 1) {
        ps += __shfl_xor(ps, o, 64);
        pd += __shfl_xor(pd, o, 64);
    }
    if (lane == 0)  { asd[node * 4 + 0] = ps; asd[node * 4 + 2] = pd; }
    if (lane == 32) { asd[node * 4 + 1] = ps; asd[node * 4 + 3] = pd; }
}

// ---------------- main: lane-parallel softmax + MLP-4 gather + FC + pool ----
__global__ __launch_bounds__(256) void main_kernel(const bf16* __restrict__ xw,
                                                   const float* __restrict__ asd,
                                                   const int* __restrict__ offs,
                                                   const int* __restrict__ ssrc,
                                                   const int* __restrict__ batch,
                                                   const float* __restrict__ bias,
                                                   const float* __restrict__ fcw,
                                                   const float* __restrict__ fcb,
                                                   float* __restrict__ gsum, int n) {
    __shared__ int   sidx[4][64];
    __shared__ float2 salp[4][64];
    int wid = threadIdx.x >> 6, lane = threadIdx.x & 63;
    int node = blockIdx.x * 4 + wid;
    if (node >= n) return;
    float4 my = ((const float4*)asd)[node];
    float ad0 = my.z, ad1 = my.w;
    int beg = offs[node], end = offs[node + 1];
    int deg = end - beg;

    float a0 = 0.f, a1 = 0.f, a2 = 0.f, a3 = 0.f;

    if (deg <= 64) {
        // ---- pass 1, lane-parallel: lane e handles edge beg+e ----
        bool act = lane < deg;
        int myidx = 0;
        float e0 = -1e30f, e1 = -1e30f;
        if (act) {
            myidx = ssrc[beg + lane];                    // coalesced
            float4 sa = ((const float4*)asd)[myidx];     // 64-wide parallel gather
            e0 = sa.x + ad0; e0 = (e0 > 0.f) ? e0 : NEG_SLOPE * e0;
            e1 = sa.y + ad1; e1 = (e1 > 0.f) ? e1 : NEG_SLOPE * e1;
        }
        float m0 = e0, m1 = e1;
        #pragma unroll
        for (int o = 32; o > 0; o >>= 1) {
            m0 = fmaxf(m0, __shfl_xor(m0, o, 64));
            m1 = fmaxf(m1, __shfl_xor(m1, o, 64));
        }
        float al0 = act ? __expf(e0 - m0) : 0.f;
        float al1 = act ? __expf(e1 - m1) : 0.f;
        float s0 = al0, s1 = al1;
        #pragma unroll
        for (int o = 32; o > 0; o >>= 1) {
            s0 += __shfl_xor(s0, o, 64);
            s1 += __shfl_xor(s1, o, 64);
        }
        float inv0 = 1.f / s0, inv1 = 1.f / s1;
        if (act) {
            sidx[wid][lane] = myidx;
            salp[wid][lane] = make_float2(al0 * inv0, al1 * inv1);
        }
        // (same-wave LDS write->read: in-order DS pipe, no barrier needed)

        // ---- pass 2: 4 independent gathers in flight ----
        int e = 0;
        for (; e + 4 <= deg; e += 4) {
            int i0 = sidx[wid][e + 0], i1 = sidx[wid][e + 1];
            int i2 = sidx[wid][e + 2], i3 = sidx[wid][e + 3];
            ushort4 v0 = ((const ushort4*)(xw + (size_t)i0 * HD))[lane];
            ushort4 v1 = ((const ushort4*)(xw + (size_t)i1 * HD))[lane];
            ushort4 v2 = ((const ushort4*)(xw + (size_t)i2 * HD))[lane];
            ushort4 v3 = ((const ushort4*)(xw + (size_t)i3 * HD))[lane];
            float2 p0 = salp[wid][e + 0], p1 = salp[wid][e + 1];
            float2 p2 = salp[wid][e + 2], p3 = salp[wid][e + 3];
            float w0 = (lane < 32) ? p0.x : p0.y;
            float w1 = (lane < 32) ? p1.x : p1.y;
            float w2 = (lane < 32) ? p2.x : p2.y;
            float w3 = (lane < 32) ? p3.x : p3.y;
            a0 += w0 * b2f(v0.x) + w1 * b2f(v1.x) + w2 * b2f(v2.x) + w3 * b2f(v3.x);
            a1 += w0 * b2f(v0.y) + w1 * b2f(v1.y) + w2 * b2f(v2.y) + w3 * b2f(v3.y);
            a2 += w0 * b2f(v0.z) + w1 * b2f(v1.z) + w2 * b2f(v2.z) + w3 * b2f(v3.z);
            a3 += w0 * b2f(v0.w) + w1 * b2f(v1.w) + w2 * b2f(v2.w) + w3 * b2f(v3.w);
        }
        for (; e < deg; e++) {
            int i0 = sidx[wid][e];
            ushort4 v0 = ((const ushort4*)(xw + (size_t)i0 * HD))[lane];
            float2 p0 = salp[wid][e];
            float w0 = (lane < 32) ? p0.x : p0.y;
            a0 += w0 * b2f(v0.x); a1 += w0 * b2f(v0.y);
            a2 += w0 * b2f(v0.z); a3 += w0 * b2f(v0.w);
        }
    } else {
        // ---- fallback (deg > 64, essentially never): serial two-pass ----
        float m0 = -1e30f, m1 = -1e30f, s0 = 0.f, s1 = 0.f;
        for (int e = beg; e < end; e++) {
            int s = ssrc[e];
            float4 sa = ((const float4*)asd)[s];
            float e0 = sa.x + ad0; e0 = (e0 > 0.f) ? e0 : NEG_SLOPE * e0;
            float e1 = sa.y + ad1; e1 = (e1 > 0.f) ? e1 : NEG_SLOPE * e1;
            float nm0 = fmaxf(m0, e0);
            s0 = s0 * __expf(m0 - nm0) + __expf(e0 - nm0); m0 = nm0;
            float nm1 = fmaxf(m1, e1);
            s1 = s1 * __expf(m1 - nm1) + __expf(e1 - nm1); m1 = nm1;
        }
        float inv0 = 1.f / s0, inv1 = 1.f / s1;
        for (int e = beg; e < end; e++) {
            int s = ssrc[e];
            float4 sa = ((const float4*)asd)[s];
            float e0 = sa.x + ad0; e0 = (e0 > 0.f) ? e0 : NEG_SLOPE * e0;
            float e1 = sa.y + ad1; e1 = (e1 > 0.f) ? e1 : NEG_SLOPE * e1;
            float al0 = __expf(e0 - m0) * inv0;
            float al1 = __expf(e1 - m1) * inv1;
            float al = (lane < 32) ? al0 : al1;
            ushort4 v = ((const ushort4*)(xw + (size_t)s * HD))[lane];
            a0 += al * b2f(v.x); a1 += al * b2f(v.y);
            a2 += al * b2f(v.z); a3 += al * b2f(v.w);
        }
    }

    // ---- epilogue: + bias, relu, FC 256->3, node log_softmax, pool ----
    float4 bv = ((const float4*)bias)[lane];
    float z0 = fmaxf(a0 + bv.x, 0.f);
    float z1 = fmaxf(a1 + bv.y, 0.f);
    float z2 = fmaxf(a2 + bv.z, 0.f);
    float z3 = fmaxf(a3 + bv.w, 0.f);

    int hd = lane * 4;
    float l0 = z0 * fcw[(hd + 0) * 3 + 0] + z1 * fcw[(hd + 1) * 3 + 0]
             + z2 * fcw[(hd + 2) * 3 + 0] + z3 * fcw[(hd + 3) * 3 + 0];
    float l1 = z0 * fcw[(hd + 0) * 3 + 1] + z1 * fcw[(hd + 1) * 3 + 1]
             + z2 * fcw[(hd + 2) * 3 + 1] + z3 * fcw[(hd + 3) * 3 + 1];
    float l2 = z0 * fcw[(hd + 0) * 3 + 2] + z1 * fcw[(hd + 1) * 3 + 2]
             + z2 * fcw[(hd + 2) * 3 + 2] + z3 * fcw[(hd + 3) * 3 + 2];
    #pragma unroll
    for (int o = 32; o > 0; o >>= 1) {
        l0 += __shfl_xor(l0, o, 64);
        l1 += __shfl_xor(l1, o, 64);
        l2 += __shfl_xor(l2, o, 64);
    }
    if (lane == 0) {
        l0 += fcb[0]; l1 += fcb[1]; l2 += fcb[2];
        float m = fmaxf(l0, fmaxf(l1, l2));
        float lse = m + __logf(__expf(l0 - m) + __expf(l1 - m) + __expf(l2 - m));
        int b = batch[node];
        atomicAdd(&gsum[b * 3 + 0], l0 - lse);
        atomicAdd(&gsum[b * 3 + 1], l1 - lse);
        atomicAdd(&gsum[b * 3 + 2], l2 - lse);
    }
}

// ---------------- final: scale by a, log_softmax over classes ----------------
__global__ void final_kernel(const float* __restrict__ gsum, const float* __restrict__ a,
                             float* __restrict__ out) {
    int g = threadIdx.x;
    if (g < N_G) {
        float av = a[0];
        float v0 = gsum[g * 3 + 0] * av;
        float v1 = gsum[g * 3 + 1] * av;
        float v2 = gsum[g * 3 + 2] * av;
        float m = fmaxf(v0, fmaxf(v1, v2));
        float lse = m + __logf(__expf(v0 - m) + __expf(v1 - m) + __expf(v2 - m));
        out[g * 3 + 0] = v0 - lse;
        out[g * 3 + 1] = v1 - lse;
        out[g * 3 + 2] = v2 - lse;
    }
}

extern "C" void kernel_launch(void* const* d_in, const int* in_sizes, int n_in,
                              void* d_out, int out_size, void* d_ws, size_t ws_size,
                              hipStream_t stream) {
    const float* x       = (const float*)d_in[0];
    const int*   ei      = (const int*)d_in[1];
    const int*   batch   = (const int*)d_in[2];
    const float* W       = (const float*)d_in[3];
    const float* att_src = (const float*)d_in[4];
    const float* att_dst = (const float*)d_in[5];
    const float* bias    = (const float*)d_in[6];
    const float* fcw     = (const float*)d_in[7];
    const float* fcb     = (const float*)d_in[8];
    const float* a_scale = (const float*)d_in[9];
    float* out = (float*)d_out;

    const int n = in_sizes[2];       // N nodes (50000)
    const int e = in_sizes[1] / 2;   // E edges (300000)

    char* ws = (char*)d_ws;
    bf16*  xw     = (bf16*)ws;                        // N*256 bf16 = 25.6 MB
    float* asd    = (float*)(ws + 25600000);          // N*4  fp32 = 800 KB
    int*   deg    = (int*)(ws + 26400000);            // N ints (counts, then cursor)
    int*   offs   = (int*)(ws + 26600000);            // N+1 ints
    int*   ssrc   = (int*)(ws + 26800256);            // (E+N) ints
    float* gsum   = (float*)(ws + 28200256);          // 64*3 fp32

    int nb256 = (n + 255) / 256;
    int eb256 = (e + 255) / 256;

    hipLaunchKernelGGL(init_kernel,     dim3(nb256), dim3(256), 0, stream, deg, gsum, n);
    hipLaunchKernelGGL(count_kernel,    dim3(eb256), dim3(256), 0, stream, ei, deg, e);
    hipLaunchKernelGGL(scan_kernel,     dim3(1), dim3(1024), 0, stream, deg, offs, n);
    hipLaunchKernelGGL(selfloop_kernel, dim3(nb256), dim3(256), 0, stream, offs, ssrc, deg, n);
    hipLaunchKernelGGL(scatter_kernel,  dim3(eb256), dim3(256), 0, stream, ei, deg, ssrc, e);
    hipLaunchKernelGGL(xw_kernel,       dim3(n / 8), dim3(256), 0, stream, x, W, xw);
    hipLaunchKernelGGL(asd_kernel,      dim3((n + 3) / 4), dim3(256), 0, stream, xw, att_src, att_dst, asd, n);
    hipLaunchKernelGGL(main_kernel,     dim3((n + 3) / 4), dim3(256), 0, stream,
                       xw, asd, offs, ssrc, batch, bias, fcw, fcb, gsum, n);
    hipLaunchKernelGGL(final_kernel,    dim3(1), dim3(64), 0, stream, gsum, a_scale, out);
}

// Round 4
// 283.530 us; speedup vs baseline: 3.2152x; 2.9248x over previous
//
#include <hip/hip_runtime.h>
#include <hip/hip_bf16.h>

typedef __hip_bfloat16 bf16;

#define N_NODES 50000
#define N_EDGES 300000
#define F_IN    128
#define HD      256
#define N_C     3
#define N_G     64
#define NEG_SLOPE 0.2f
#define NPART   512   // gsum privatization partitions

__device__ __forceinline__ float b2f(unsigned short u) {
    return __uint_as_float(((unsigned int)u) << 16);
}

// ---------------- init: deg=1 (self loop), gsumP=0 ----------------
__global__ void init_kernel(int* deg, float* gsumP, int n) {
    int i = blockIdx.x * blockDim.x + threadIdx.x;
    if (i < n) deg[i] = 1;
    if (i < N_G * N_C * NPART) gsumP[i] = 0.f;
}

// ---------------- count in-degrees ----------------
__global__ void count_kernel(const int* __restrict__ ei, int* deg, int e) {
    int i = blockIdx.x * blockDim.x + threadIdx.x;
    if (i < e) atomicAdd(&deg[ei[e + i]], 1);
}

// ---------------- exclusive scan (single block, 1024 thr) ----------------
__global__ __launch_bounds__(1024) void scan_kernel(const int* __restrict__ deg,
                                                    int* __restrict__ offs, int n) {
    __shared__ int wsum[16];
    __shared__ int blocktot;
    int tid = threadIdx.x, lane = tid & 63, wid = tid >> 6;
    int carry = 0;
    for (int base = 0; base < n; base += 1024) {
        int i = base + tid;
        int v = (i < n) ? deg[i] : 0;
        int x = v;
        #pragma unroll
        for (int o = 1; o < 64; o <<= 1) {
            int y = __shfl_up(x, o, 64);
            if (lane >= o) x += y;
        }
        if (lane == 63) wsum[wid] = x;
        __syncthreads();
        if (tid == 0) {
            int run = 0;
            for (int w = 0; w < 16; w++) { int t = wsum[w]; wsum[w] = run; run += t; }
            blocktot = run;
        }
        __syncthreads();
        if (i < n) offs[i] = carry + wsum[wid] + (x - v);
        carry += blocktot;
        __syncthreads();
    }
    if (tid == 0) offs[n] = carry;
}

// ---------------- place self-loops, set cursors ----------------
__global__ void selfloop_kernel(const int* __restrict__ offs, int* __restrict__ ssrc,
                                int* __restrict__ cursor, int n) {
    int i = blockIdx.x * blockDim.x + threadIdx.x;
    if (i < n) {
        int o = offs[i];
        ssrc[o] = i;
        cursor[i] = o + 1;
    }
}

// ---------------- scatter edges into CSR by target ----------------
__global__ void scatter_kernel(const int* __restrict__ ei, int* cursor,
                               int* __restrict__ ssrc, int e) {
    int i = blockIdx.x * blockDim.x + threadIdx.x;
    if (i < e) {
        int s = ei[i];
        int t = ei[e + i];
        int p = atomicAdd(&cursor[t], 1);
        ssrc[p] = s;
    }
}

// ---------------- xw = x @ W  (8 nodes per 256-thread block), fp32 in, bf16 out
__global__ __launch_bounds__(256) void xw_kernel(const float* __restrict__ x,
                                                 const float* __restrict__ W,
                                                 bf16* __restrict__ xw) {
    __shared__ float xs[8 * F_IN];
    int t = threadIdx.x;           // == output column hd (0..255)
    int nb = blockIdx.x * 8;
    ((float4*)xs)[t] = ((const float4*)(x + (size_t)nb * F_IN))[t];
    __syncthreads();
    float acc[8] = {0.f, 0.f, 0.f, 0.f, 0.f, 0.f, 0.f, 0.f};
    for (int f = 0; f < F_IN; f++) {
        float w = W[f * HD + t];
        #pragma unroll
        for (int k = 0; k < 8; k++) acc[k] += xs[k * F_IN + f] * w;
    }
    bf16* outp = xw + (size_t)nb * HD + t;
    #pragma unroll
    for (int k = 0; k < 8; k++) outp[k * HD] = __float2bfloat16(acc[k]);
}

// ---------------- per-node attention coefficients a_s, a_d ----------------
// asd layout: [n][4] = {as_h0, as_h1, ad_h0, ad_h1}
__global__ __launch_bounds__(256) void asd_kernel(const bf16* __restrict__ xw,
                                                  const float* __restrict__ att_src,
                                                  const float* __restrict__ att_dst,
                                                  float* __restrict__ asd, int n) {
    int wid = threadIdx.x >> 6, lane = threadIdx.x & 63;
    int node = blockIdx.x * 4 + wid;
    if (node >= n) return;
    ushort4 v = ((const ushort4*)(xw + (size_t)node * HD))[lane];
    float4 s = ((const float4*)att_src)[lane];
    float4 d = ((const float4*)att_dst)[lane];
    float ps = b2f(v.x) * s.x + b2f(v.y) * s.y + b2f(v.z) * s.z + b2f(v.w) * s.w;
    float pd = b2f(v.x) * d.x + b2f(v.y) * d.y + b2f(v.z) * d.z + b2f(v.w) * d.w;
    #pragma unroll
    for (int o = 16; o > 0; o >>= 1) {
        ps += __shfl_xor(ps, o, 64);
        pd += __shfl_xor(pd, o, 64);
    }
    if (lane == 0)  { asd[node * 4 + 0] = ps; asd[node * 4 + 2] = pd; }
    if (lane == 32) { asd[node * 4 + 1] = ps; asd[node * 4 + 3] = pd; }
}

// ---------------- main: lane-parallel softmax + MLP-4 gather + FC +
//                  PRIVATIZED pool (atomics spread over NPART partitions) ----
__global__ __launch_bounds__(256) void main_kernel(const bf16* __restrict__ xw,
                                                   const float* __restrict__ asd,
                                                   const int* __restrict__ offs,
                                                   const int* __restrict__ ssrc,
                                                   const int* __restrict__ batch,
                                                   const float* __restrict__ bias,
                                                   const float* __restrict__ fcw,
                                                   const float* __restrict__ fcb,
                                                   float* __restrict__ gsumP, int n) {
    __shared__ int   sidx[4][64];
    __shared__ float2 salp[4][64];
    int wid = threadIdx.x >> 6, lane = threadIdx.x & 63;
    int node = blockIdx.x * 4 + wid;
    if (node >= n) return;
    float4 my = ((const float4*)asd)[node];
    float ad0 = my.z, ad1 = my.w;
    int beg = offs[node], end = offs[node + 1];
    int deg = end - beg;

    float a0 = 0.f, a1 = 0.f, a2 = 0.f, a3 = 0.f;

    if (deg <= 64) {
        bool act = lane < deg;
        int myidx = 0;
        float e0 = -1e30f, e1 = -1e30f;
        if (act) {
            myidx = ssrc[beg + lane];                    // coalesced
            float4 sa = ((const float4*)asd)[myidx];     // 64-wide parallel gather
            e0 = sa.x + ad0; e0 = (e0 > 0.f) ? e0 : NEG_SLOPE * e0;
            e1 = sa.y + ad1; e1 = (e1 > 0.f) ? e1 : NEG_SLOPE * e1;
        }
        float m0 = e0, m1 = e1;
        #pragma unroll
        for (int o = 32; o > 0; o >>= 1) {
            m0 = fmaxf(m0, __shfl_xor(m0, o, 64));
            m1 = fmaxf(m1, __shfl_xor(m1, o, 64));
        }
        float al0 = act ? __expf(e0 - m0) : 0.f;
        float al1 = act ? __expf(e1 - m1) : 0.f;
        float s0 = al0, s1 = al1;
        #pragma unroll
        for (int o = 32; o > 0; o >>= 1) {
            s0 += __shfl_xor(s0, o, 64);
            s1 += __shfl_xor(s1, o, 64);
        }
        float inv0 = 1.f / s0, inv1 = 1.f / s1;
        if (act) {
            sidx[wid][lane] = myidx;
            salp[wid][lane] = make_float2(al0 * inv0, al1 * inv1);
        }
        // same-wave LDS write->read: in-order DS pipe, no barrier needed

        int e = 0;
        for (; e + 4 <= deg; e += 4) {
            int i0 = sidx[wid][e + 0], i1 = sidx[wid][e + 1];
            int i2 = sidx[wid][e + 2], i3 = sidx[wid][e + 3];
            ushort4 v0 = ((const ushort4*)(xw + (size_t)i0 * HD))[lane];
            ushort4 v1 = ((const ushort4*)(xw + (size_t)i1 * HD))[lane];
            ushort4 v2 = ((const ushort4*)(xw + (size_t)i2 * HD))[lane];
            ushort4 v3 = ((const ushort4*)(xw + (size_t)i3 * HD))[lane];
            float2 p0 = salp[wid][e + 0], p1 = salp[wid][e + 1];
            float2 p2 = salp[wid][e + 2], p3 = salp[wid][e + 3];
            float w0 = (lane < 32) ? p0.x : p0.y;
            float w1 = (lane < 32) ? p1.x : p1.y;
            float w2 = (lane < 32) ? p2.x : p2.y;
            float w3 = (lane < 32) ? p3.x : p3.y;
            a0 += w0 * b2f(v0.x) + w1 * b2f(v1.x) + w2 * b2f(v2.x) + w3 * b2f(v3.x);
            a1 += w0 * b2f(v0.y) + w1 * b2f(v1.y) + w2 * b2f(v2.y) + w3 * b2f(v3.y);
            a2 += w0 * b2f(v0.z) + w1 * b2f(v1.z) + w2 * b2f(v2.z) + w3 * b2f(v3.z);
            a3 += w0 * b2f(v0.w) + w1 * b2f(v1.w) + w2 * b2f(v2.w) + w3 * b2f(v3.w);
        }
        for (; e < deg; e++) {
            int i0 = sidx[wid][e];
            ushort4 v0 = ((const ushort4*)(xw + (size_t)i0 * HD))[lane];
            float2 p0 = salp[wid][e];
            float w0 = (lane < 32) ? p0.x : p0.y;
            a0 += w0 * b2f(v0.x); a1 += w0 * b2f(v0.y);
            a2 += w0 * b2f(v0.z); a3 += w0 * b2f(v0.w);
        }
    } else {
        // fallback (deg > 64, essentially never): serial two-pass
        float m0 = -1e30f, m1 = -1e30f, s0 = 0.f, s1 = 0.f;
        for (int e = beg; e < end; e++) {
            int s = ssrc[e];
            float4 sa = ((const float4*)asd)[s];
            float e0 = sa.x + ad0; e0 = (e0 > 0.f) ? e0 : NEG_SLOPE * e0;
            float e1 = sa.y + ad1; e1 = (e1 > 0.f) ? e1 : NEG_SLOPE * e1;
            float nm0 = fmaxf(m0, e0);
            s0 = s0 * __expf(m0 - nm0) + __expf(e0 - nm0); m0 = nm0;
            float nm1 = fmaxf(m1, e1);
            s1 = s1 * __expf(m1 - nm1) + __expf(e1 - nm1); m1 = nm1;
        }
        float inv0 = 1.f / s0, inv1 = 1.f / s1;
        for (int e = beg; e < end; e++) {
            int s = ssrc[e];
            float4 sa = ((const float4*)asd)[s];
            float e0 = sa.x + ad0; e0 = (e0 > 0.f) ? e0 : NEG_SLOPE * e0;
            float e1 = sa.y + ad1; e1 = (e1 > 0.f) ? e1 : NEG_SLOPE * e1;
            float al0 = __expf(e0 - m0) * inv0;
            float al1 = __expf(e1 - m1) * inv1;
            float al = (lane < 32) ? al0 : al1;
            ushort4 v = ((const ushort4*)(xw + (size_t)s * HD))[lane];
            a0 += al * b2f(v.x); a1 += al * b2f(v.y);
            a2 += al * b2f(v.z); a3 += al * b2f(v.w);
        }
    }

    // ---- epilogue: + bias, relu, FC 256->3, node log_softmax, pool ----
    float4 bv = ((const float4*)bias)[lane];
    float z0 = fmaxf(a0 + bv.x, 0.f);
    float z1 = fmaxf(a1 + bv.y, 0.f);
    float z2 = fmaxf(a2 + bv.z, 0.f);
    float z3 = fmaxf(a3 + bv.w, 0.f);

    int hd = lane * 4;
    float l0 = z0 * fcw[(hd + 0) * 3 + 0] + z1 * fcw[(hd + 1) * 3 + 0]
             + z2 * fcw[(hd + 2) * 3 + 0] + z3 * fcw[(hd + 3) * 3 + 0];
    float l1 = z0 * fcw[(hd + 0) * 3 + 1] + z1 * fcw[(hd + 1) * 3 + 1]
             + z2 * fcw[(hd + 2) * 3 + 1] + z3 * fcw[(hd + 3) * 3 + 1];
    float l2 = z0 * fcw[(hd + 0) * 3 + 2] + z1 * fcw[(hd + 1) * 3 + 2]
             + z2 * fcw[(hd + 2) * 3 + 2] + z3 * fcw[(hd + 3) * 3 + 2];
    #pragma unroll
    for (int o = 32; o > 0; o >>= 1) {
        l0 += __shfl_xor(l0, o, 64);
        l1 += __shfl_xor(l1, o, 64);
        l2 += __shfl_xor(l2, o, 64);
    }
    if (lane == 0) {
        l0 += fcb[0]; l1 += fcb[1]; l2 += fcb[2];
        float m = fmaxf(l0, fmaxf(l1, l2));
        float lse = m + __logf(__expf(l0 - m) + __expf(l1 - m) + __expf(l2 - m));
        int b = batch[node];
        int part = blockIdx.x & (NPART - 1);
        // gsumP layout: [class_flat][NPART] -> coalesced reduce later
        atomicAdd(&gsumP[(b * 3 + 0) * NPART + part], l0 - lse);
        atomicAdd(&gsumP[(b * 3 + 1) * NPART + part], l1 - lse);
        atomicAdd(&gsumP[(b * 3 + 2) * NPART + part], l2 - lse);
    }
}

// ---------------- final: reduce partitions, scale by a, log_softmax --------
__global__ __launch_bounds__(64) void final_kernel(const float* __restrict__ gsumP,
                                                   const float* __restrict__ a,
                                                   float* __restrict__ out) {
    int g = blockIdx.x;        // graph id, 64 blocks
    int lane = threadIdx.x;    // 64 threads
    float v[3];
    #pragma unroll
    for (int c = 0; c < 3; c++) {
        float s = 0.f;
        for (int p = lane; p < NPART; p += 64)
            s += gsumP[(g * 3 + c) * NPART + p];
        #pragma unroll
        for (int o = 32; o > 0; o >>= 1) s += __shfl_xor(s, o, 64);
        v[c] = s;
    }
    if (lane == 0) {
        float av = a[0];
        float v0 = v[0] * av, v1 = v[1] * av, v2 = v[2] * av;
        float m = fmaxf(v0, fmaxf(v1, v2));
        float lse = m + __logf(__expf(v0 - m) + __expf(v1 - m) + __expf(v2 - m));
        out[g * 3 + 0] = v0 - lse;
        out[g * 3 + 1] = v1 - lse;
        out[g * 3 + 2] = v2 - lse;
    }
}

extern "C" void kernel_launch(void* const* d_in, const int* in_sizes, int n_in,
                              void* d_out, int out_size, void* d_ws, size_t ws_size,
                              hipStream_t stream) {
    const float* x       = (const float*)d_in[0];
    const int*   ei      = (const int*)d_in[1];
    const int*   batch   = (const int*)d_in[2];
    const float* W       = (const float*)d_in[3];
    const float* att_src = (const float*)d_in[4];
    const float* att_dst = (const float*)d_in[5];
    const float* bias    = (const float*)d_in[6];
    const float* fcw     = (const float*)d_in[7];
    const float* fcb     = (const float*)d_in[8];
    const float* a_scale = (const float*)d_in[9];
    float* out = (float*)d_out;

    const int n = in_sizes[2];       // N nodes (50000)
    const int e = in_sizes[1] / 2;   // E edges (300000)

    char* ws = (char*)d_ws;
    bf16*  xw     = (bf16*)ws;                        // N*256 bf16 = 25.6 MB
    float* asd    = (float*)(ws + 25600000);          // N*4  fp32 = 800 KB
    int*   deg    = (int*)(ws + 26400000);            // N ints (counts, then cursor)
    int*   offs   = (int*)(ws + 26600000);            // N+1 ints
    int*   ssrc   = (int*)(ws + 26800256);            // (E+N) ints
    float* gsumP  = (float*)(ws + 28200256);          // 192*512 fp32 = 393 KB

    int nb256 = (n + 255) / 256;
    int eb256 = (e + 255) / 256;
    int ib256 = (N_G * N_C * NPART + 255) / 256;      // init grid covers gsumP
    if (ib256 < nb256) ib256 = nb256;

    hipLaunchKernelGGL(init_kernel,     dim3(ib256), dim3(256), 0, stream, deg, gsumP, n);
    hipLaunchKernelGGL(count_kernel,    dim3(eb256), dim3(256), 0, stream, ei, deg, e);
    hipLaunchKernelGGL(scan_kernel,     dim3(1), dim3(1024), 0, stream, deg, offs, n);
    hipLaunchKernelGGL(selfloop_kernel, dim3(nb256), dim3(256), 0, stream, offs, ssrc, deg, n);
    hipLaunchKernelGGL(scatter_kernel,  dim3(eb256), dim3(256), 0, stream, ei, deg, ssrc, e);
    hipLaunchKernelGGL(xw_kernel,       dim3(n / 8), dim3(256), 0, stream, x, W, xw);
    hipLaunchKernelGGL(asd_kernel,      dim3((n + 3) / 4), dim3(256), 0, stream, xw, att_src, att_dst, asd, n);
    hipLaunchKernelGGL(main_kernel,     dim3((n + 3) / 4), dim3(256), 0, stream,
                       xw, asd, offs, ssrc, batch, bias, fcw, fcb, gsumP, n);
    hipLaunchKernelGGL(final_kernel,    dim3(N_G), dim3(64), 0, stream, gsumP, a_scale, out);
}

// Round 5
// 250.089 us; speedup vs baseline: 3.6451x; 1.1337x over previous
//
#include <hip/hip_runtime.h>
#include <hip/hip_bf16.h>

typedef __hip_bfloat16 bf16;
typedef __attribute__((ext_vector_type(8))) short bf16x8;
typedef __attribute__((ext_vector_type(4))) float f32x4;

#define N_NODES 50000
#define N_EDGES 300000
#define F_IN    128
#define HD      256
#define N_C     3
#define N_G     64
#define NEG_SLOPE 0.2f
#define NPART   512   // gsum privatization partitions

__device__ __forceinline__ float b2f(unsigned short u) {
    return __uint_as_float(((unsigned int)u) << 16);
}
// fp32 -> bf16 bits, round-nearest-even (finite inputs)
__device__ __forceinline__ unsigned short f2bs(float f) {
    unsigned int u = __float_as_uint(f);
    return (unsigned short)((u + 0x7FFFu + ((u >> 16) & 1u)) >> 16);
}

// ---------------- init: deg=1 (self loop), gsumP=0 ----------------
__global__ void init_kernel(int* deg, float* gsumP, int n) {
    int i = blockIdx.x * blockDim.x + threadIdx.x;
    if (i < n) deg[i] = 1;
    if (i < N_G * N_C * NPART) gsumP[i] = 0.f;
}

// ---------------- count in-degrees ----------------
__global__ void count_kernel(const int* __restrict__ ei, int* deg, int e) {
    int i = blockIdx.x * blockDim.x + threadIdx.x;
    if (i < e) atomicAdd(&deg[ei[e + i]], 1);
}

// ---------------- exclusive scan (single block, 1024 thr) ----------------
__global__ __launch_bounds__(1024) void scan_kernel(const int* __restrict__ deg,
                                                    int* __restrict__ offs, int n) {
    __shared__ int wsum[16];
    __shared__ int blocktot;
    int tid = threadIdx.x, lane = tid & 63, wid = tid >> 6;
    int carry = 0;
    for (int base = 0; base < n; base += 1024) {
        int i = base + tid;
        int v = (i < n) ? deg[i] : 0;
        int x = v;
        #pragma unroll
        for (int o = 1; o < 64; o <<= 1) {
            int y = __shfl_up(x, o, 64);
            if (lane >= o) x += y;
        }
        if (lane == 63) wsum[wid] = x;
        __syncthreads();
        if (tid == 0) {
            int run = 0;
            for (int w = 0; w < 16; w++) { int t = wsum[w]; wsum[w] = run; run += t; }
            blocktot = run;
        }
        __syncthreads();
        if (i < n) offs[i] = carry + wsum[wid] + (x - v);
        carry += blocktot;
        __syncthreads();
    }
    if (tid == 0) offs[n] = carry;
}

// ---------------- place self-loops, set cursors ----------------
__global__ void selfloop_kernel(const int* __restrict__ offs, int* __restrict__ ssrc,
                                int* __restrict__ cursor, int n) {
    int i = blockIdx.x * blockDim.x + threadIdx.x;
    if (i < n) {
        int o = offs[i];
        ssrc[o] = i;
        cursor[i] = o + 1;
    }
}

// ---------------- scatter edges into CSR by target ----------------
__global__ void scatter_kernel(const int* __restrict__ ei, int* cursor,
                               int* __restrict__ ssrc, int e) {
    int i = blockIdx.x * blockDim.x + threadIdx.x;
    if (i < e) {
        int s = ei[i];
        int t = ei[e + i];
        int p = atomicAdd(&cursor[t], 1);
        ssrc[p] = s;
    }
}

// ---------------- WT[hd][f] = bf16(W[f][hd])  (128x256 -> 256x128) ----------
__global__ void wt_kernel(const float* __restrict__ W, unsigned short* __restrict__ WT) {
    int o = blockIdx.x * blockDim.x + threadIdx.x;   // o = hd*128 + f
    if (o < HD * F_IN) {
        int f = o & (F_IN - 1);
        int hd = o >> 7;
        WT[o] = f2bs(W[f * HD + hd]);
    }
}

// ---------------- xw = x @ W via MFMA (bf16), fused asd epilogue ------------
// wave: 16 rows x 256 cols. A[m=lane&15][k=quad*8+j], B[n=lane&15][k=quad*8+j],
// D[col=lane&15, row=quad*4+reg]  (verified layouts, learn_hip m89/m91)
__global__ __launch_bounds__(256) void xw_mfma_kernel(const float* __restrict__ x,
                                                      const unsigned short* __restrict__ WT,
                                                      bf16* __restrict__ xw,
                                                      const float* __restrict__ att_src,
                                                      const float* __restrict__ att_dst,
                                                      float* __restrict__ asd, int n) {
    int wid = threadIdx.x >> 6, lane = threadIdx.x & 63;
    int rowbase = blockIdx.x * 64 + wid * 16;
    if (rowbase >= n) return;                 // n % 16 == 0: whole wave valid or not
    int r16  = lane & 15;                     // A-row / B-col / D-col within tile
    int quad = lane >> 4;                     // k sub-chunk (A/B); D row-group

    // ---- A fragments: K=128 as 4 chunks of 32; 8 contiguous fp32 per lane ----
    bf16x8 afrag[4];
    const float* xrow = x + (size_t)(rowbase + r16) * F_IN + quad * 8;
    #pragma unroll
    for (int c = 0; c < 4; c++) {
        float4 f0 = *(const float4*)(xrow + c * 32);
        float4 f1 = *(const float4*)(xrow + c * 32 + 4);
        bf16x8 a;
        a[0] = (short)f2bs(f0.x); a[1] = (short)f2bs(f0.y);
        a[2] = (short)f2bs(f0.z); a[3] = (short)f2bs(f0.w);
        a[4] = (short)f2bs(f1.x); a[5] = (short)f2bs(f1.y);
        a[6] = (short)f2bs(f1.z); a[7] = (short)f2bs(f1.w);
        afrag[c] = a;
    }

    float ps0[4] = {0,0,0,0}, ps1[4] = {0,0,0,0};
    float pd0[4] = {0,0,0,0}, pd1[4] = {0,0,0,0};

    const unsigned short* wtbase = WT + (size_t)r16 * F_IN + quad * 8;
    for (int t = 0; t < 16; t++) {
        int colbase = t * 16;
        const unsigned short* wtrow = wtbase + (size_t)colbase * F_IN;
        f32x4 acc = {0.f, 0.f, 0.f, 0.f};
        #pragma unroll
        for (int c = 0; c < 4; c++) {
            bf16x8 b = *(const bf16x8*)(wtrow + c * 32);
            acc = __builtin_amdgcn_mfma_f32_16x16x32_bf16(afrag[c], b, acc, 0, 0, 0);
        }
        float sv = att_src[colbase + r16];
        float dv = att_dst[colbase + r16];
        unsigned short* op = (unsigned short*)xw
                           + (size_t)(rowbase + quad * 4) * HD + colbase + r16;
        #pragma unroll
        for (int r = 0; r < 4; r++) {
            float v = acc[r];
            op[(size_t)r * HD] = f2bs(v);
            if (t < 8) { ps0[r] += v * sv; pd0[r] += v * dv; }
            else       { ps1[r] += v * sv; pd1[r] += v * dv; }
        }
    }

    // reduce partials across the 16 lanes of each quad (xor 1,2,4,8 stays in-quad)
    #pragma unroll
    for (int o = 1; o <= 8; o <<= 1) {
        #pragma unroll
        for (int r = 0; r < 4; r++) {
            ps0[r] += __shfl_xor(ps0[r], o, 64);
            ps1[r] += __shfl_xor(ps1[r], o, 64);
            pd0[r] += __shfl_xor(pd0[r], o, 64);
            pd1[r] += __shfl_xor(pd1[r], o, 64);
        }
    }
    if (r16 == 0) {
        #pragma unroll
        for (int r = 0; r < 4; r++) {
            int row = rowbase + quad * 4 + r;
            float4 v; v.x = ps0[r]; v.y = ps1[r]; v.z = pd0[r]; v.w = pd1[r];
            ((float4*)asd)[row] = v;   // {as_h0, as_h1, ad_h0, ad_h1}
        }
    }
}

// ---------------- main: lane-parallel softmax + MLP-4 gather + FC +
//                  privatized pool ----------------
__global__ __launch_bounds__(256) void main_kernel(const bf16* __restrict__ xw,
                                                   const float* __restrict__ asd,
                                                   const int* __restrict__ offs,
                                                   const int* __restrict__ ssrc,
                                                   const int* __restrict__ batch,
                                                   const float* __restrict__ bias,
                                                   const float* __restrict__ fcw,
                                                   const float* __restrict__ fcb,
                                                   float* __restrict__ gsumP, int n) {
    __shared__ int   sidx[4][64];
    __shared__ float2 salp[4][64];
    int wid = threadIdx.x >> 6, lane = threadIdx.x & 63;
    int node = blockIdx.x * 4 + wid;
    if (node >= n) return;
    float4 my = ((const float4*)asd)[node];
    float ad0 = my.z, ad1 = my.w;
    int beg = offs[node], end = offs[node + 1];
    int deg = end - beg;

    float a0 = 0.f, a1 = 0.f, a2 = 0.f, a3 = 0.f;

    if (deg <= 64) {
        bool act = lane < deg;
        int myidx = 0;
        float e0 = -1e30f, e1 = -1e30f;
        if (act) {
            myidx = ssrc[beg + lane];                    // coalesced
            float4 sa = ((const float4*)asd)[myidx];     // 64-wide parallel gather
            e0 = sa.x + ad0; e0 = (e0 > 0.f) ? e0 : NEG_SLOPE * e0;
            e1 = sa.y + ad1; e1 = (e1 > 0.f) ? e1 : NEG_SLOPE * e1;
        }
        float m0 = e0, m1 = e1;
        #pragma unroll
        for (int o = 32; o > 0; o >>= 1) {
            m0 = fmaxf(m0, __shfl_xor(m0, o, 64));
            m1 = fmaxf(m1, __shfl_xor(m1, o, 64));
        }
        float al0 = act ? __expf(e0 - m0) : 0.f;
        float al1 = act ? __expf(e1 - m1) : 0.f;
        float s0 = al0, s1 = al1;
        #pragma unroll
        for (int o = 32; o > 0; o >>= 1) {
            s0 += __shfl_xor(s0, o, 64);
            s1 += __shfl_xor(s1, o, 64);
        }
        float inv0 = 1.f / s0, inv1 = 1.f / s1;
        if (act) {
            sidx[wid][lane] = myidx;
            salp[wid][lane] = make_float2(al0 * inv0, al1 * inv1);
        }
        // same-wave LDS write->read: in-order DS pipe, no barrier needed

        int e = 0;
        for (; e + 4 <= deg; e += 4) {
            int i0 = sidx[wid][e + 0], i1 = sidx[wid][e + 1];
            int i2 = sidx[wid][e + 2], i3 = sidx[wid][e + 3];
            ushort4 v0 = ((const ushort4*)(xw + (size_t)i0 * HD))[lane];
            ushort4 v1 = ((const ushort4*)(xw + (size_t)i1 * HD))[lane];
            ushort4 v2 = ((const ushort4*)(xw + (size_t)i2 * HD))[lane];
            ushort4 v3 = ((const ushort4*)(xw + (size_t)i3 * HD))[lane];
            float2 p0 = salp[wid][e + 0], p1 = salp[wid][e + 1];
            float2 p2 = salp[wid][e + 2], p3 = salp[wid][e + 3];
            float w0 = (lane < 32) ? p0.x : p0.y;
            float w1 = (lane < 32) ? p1.x : p1.y;
            float w2 = (lane < 32) ? p2.x : p2.y;
            float w3 = (lane < 32) ? p3.x : p3.y;
            a0 += w0 * b2f(v0.x) + w1 * b2f(v1.x) + w2 * b2f(v2.x) + w3 * b2f(v3.x);
            a1 += w0 * b2f(v0.y) + w1 * b2f(v1.y) + w2 * b2f(v2.y) + w3 * b2f(v3.y);
            a2 += w0 * b2f(v0.z) + w1 * b2f(v1.z) + w2 * b2f(v2.z) + w3 * b2f(v3.z);
            a3 += w0 * b2f(v0.w) + w1 * b2f(v1.w) + w2 * b2f(v2.w) + w3 * b2f(v3.w);
        }
        for (; e < deg; e++) {
            int i0 = sidx[wid][e];
            ushort4 v0 = ((const ushort4*)(xw + (size_t)i0 * HD))[lane];
            float2 p0 = salp[wid][e];
            float w0 = (lane < 32) ? p0.x : p0.y;
            a0 += w0 * b2f(v0.x); a1 += w0 * b2f(v0.y);
            a2 += w0 * b2f(v0.z); a3 += w0 * b2f(v0.w);
        }
    } else {
        // fallback (deg > 64, essentially never): serial two-pass
        float m0 = -1e30f, m1 = -1e30f, s0 = 0.f, s1 = 0.f;
        for (int e = beg; e < end; e++) {
            int s = ssrc[e];
            float4 sa = ((const float4*)asd)[s];
            float e0 = sa.x + ad0; e0 = (e0 > 0.f) ? e0 : NEG_SLOPE * e0;
            float e1 = sa.y + ad1; e1 = (e1 > 0.f) ? e1 : NEG_SLOPE * e1;
            float nm0 = fmaxf(m0, e0);
            s0 = s0 * __expf(m0 - nm0) + __expf(e0 - nm0); m0 = nm0;
            float nm1 = fmaxf(m1, e1);
            s1 = s1 * __expf(m1 - nm1) + __expf(e1 - nm1); m1 = nm1;
        }
        float inv0 = 1.f / s0, inv1 = 1.f / s1;
        for (int e = beg; e < end; e++) {
            int s = ssrc[e];
            float4 sa = ((const float4*)asd)[s];
            float e0 = sa.x + ad0; e0 = (e0 > 0.f) ? e0 : NEG_SLOPE * e0;
            float e1 = sa.y + ad1; e1 = (e1 > 0.f) ? e1 : NEG_SLOPE * e1;
            float al0 = __expf(e0 - m0) * inv0;
            float al1 = __expf(e1 - m1) * inv1;
            float al = (lane < 32) ? al0 : al1;
            ushort4 v = ((const ushort4*)(xw + (size_t)s * HD))[lane];
            a0 += al * b2f(v.x); a1 += al * b2f(v.y);
            a2 += al * b2f(v.z); a3 += al * b2f(v.w);
        }
    }

    // ---- epilogue: + bias, relu, FC 256->3, node log_softmax, pool ----
    float4 bv = ((const float4*)bias)[lane];
    float z0 = fmaxf(a0 + bv.x, 0.f);
    float z1 = fmaxf(a1 + bv.y, 0.f);
    float z2 = fmaxf(a2 + bv.z, 0.f);
    float z3 = fmaxf(a3 + bv.w, 0.f);

    int hd = lane * 4;
    float l0 = z0 * fcw[(hd + 0) * 3 + 0] + z1 * fcw[(hd + 1) * 3 + 0]
             + z2 * fcw[(hd + 2) * 3 + 0] + z3 * fcw[(hd + 3) * 3 + 0];
    float l1 = z0 * fcw[(hd + 0) * 3 + 1] + z1 * fcw[(hd + 1) * 3 + 1]
             + z2 * fcw[(hd + 2) * 3 + 1] + z3 * fcw[(hd + 3) * 3 + 1];
    float l2 = z0 * fcw[(hd + 0) * 3 + 2] + z1 * fcw[(hd + 1) * 3 + 2]
             + z2 * fcw[(hd + 2) * 3 + 2] + z3 * fcw[(hd + 3) * 3 + 2];
    #pragma unroll
    for (int o = 32; o > 0; o >>= 1) {
        l0 += __shfl_xor(l0, o, 64);
        l1 += __shfl_xor(l1, o, 64);
        l2 += __shfl_xor(l2, o, 64);
    }
    if (lane == 0) {
        l0 += fcb[0]; l1 += fcb[1]; l2 += fcb[2];
        float m = fmaxf(l0, fmaxf(l1, l2));
        float lse = m + __logf(__expf(l0 - m) + __expf(l1 - m) + __expf(l2 - m));
        int b = batch[node];
        int part = blockIdx.x & (NPART - 1);
        atomicAdd(&gsumP[(b * 3 + 0) * NPART + part], l0 - lse);
        atomicAdd(&gsumP[(b * 3 + 1) * NPART + part], l1 - lse);
        atomicAdd(&gsumP[(b * 3 + 2) * NPART + part], l2 - lse);
    }
}

// ---------------- final: reduce partitions, scale by a, log_softmax --------
__global__ __launch_bounds__(64) void final_kernel(const float* __restrict__ gsumP,
                                                   const float* __restrict__ a,
                                                   float* __restrict__ out) {
    int g = blockIdx.x;        // graph id, 64 blocks
    int lane = threadIdx.x;    // 64 threads
    float v[3];
    #pragma unroll
    for (int c = 0; c < 3; c++) {
        float s = 0.f;
        for (int p = lane; p < NPART; p += 64)
            s += gsumP[(g * 3 + c) * NPART + p];
        #pragma unroll
        for (int o = 32; o > 0; o >>= 1) s += __shfl_xor(s, o, 64);
        v[c] = s;
    }
    if (lane == 0) {
        float av = a[0];
        float v0 = v[0] * av, v1 = v[1] * av, v2 = v[2] * av;
        float m = fmaxf(v0, fmaxf(v1, v2));
        float lse = m + __logf(__expf(v0 - m) + __expf(v1 - m) + __expf(v2 - m));
        out[g * 3 + 0] = v0 - lse;
        out[g * 3 + 1] = v1 - lse;
        out[g * 3 + 2] = v2 - lse;
    }
}

extern "C" void kernel_launch(void* const* d_in, const int* in_sizes, int n_in,
                              void* d_out, int out_size, void* d_ws, size_t ws_size,
                              hipStream_t stream) {
    const float* x       = (const float*)d_in[0];
    const int*   ei      = (const int*)d_in[1];
    const int*   batch   = (const int*)d_in[2];
    const float* W       = (const float*)d_in[3];
    const float* att_src = (const float*)d_in[4];
    const float* att_dst = (const float*)d_in[5];
    const float* bias    = (const float*)d_in[6];
    const float* fcw     = (const float*)d_in[7];
    const float* fcb     = (const float*)d_in[8];
    const float* a_scale = (const float*)d_in[9];
    float* out = (float*)d_out;

    const int n = in_sizes[2];       // N nodes (50000)
    const int e = in_sizes[1] / 2;   // E edges (300000)

    char* ws = (char*)d_ws;
    bf16*  xw     = (bf16*)ws;                        // N*256 bf16 = 25.6 MB
    float* asd    = (float*)(ws + 25600000);          // N*4  fp32 = 800 KB
    int*   deg    = (int*)(ws + 26400000);            // N ints (counts, then cursor)
    int*   offs   = (int*)(ws + 26600000);            // N+1 ints
    int*   ssrc   = (int*)(ws + 26800256);            // (E+N) ints
    float* gsumP  = (float*)(ws + 28200256);          // 192*512 fp32 = 393 KB
    unsigned short* WTb = (unsigned short*)(ws + 28593472);  // 256*128 bf16 = 64 KB

    int nb256 = (n + 255) / 256;
    int eb256 = (e + 255) / 256;
    int ib256 = (N_G * N_C * NPART + 255) / 256;      // init grid covers gsumP
    if (ib256 < nb256) ib256 = nb256;

    hipLaunchKernelGGL(init_kernel,     dim3(ib256), dim3(256), 0, stream, deg, gsumP, n);
    hipLaunchKernelGGL(count_kernel,    dim3(eb256), dim3(256), 0, stream, ei, deg, e);
    hipLaunchKernelGGL(scan_kernel,     dim3(1), dim3(1024), 0, stream, deg, offs, n);
    hipLaunchKernelGGL(selfloop_kernel, dim3(nb256), dim3(256), 0, stream, offs, ssrc, deg, n);
    hipLaunchKernelGGL(scatter_kernel,  dim3(eb256), dim3(256), 0, stream, ei, deg, ssrc, e);
    hipLaunchKernelGGL(wt_kernel,       dim3((HD * F_IN + 255) / 256), dim3(256), 0, stream, W, WTb);
    hipLaunchKernelGGL(xw_mfma_kernel,  dim3((n + 63) / 64), dim3(256), 0, stream,
                       x, WTb, xw, att_src, att_dst, asd, n);
    hipLaunchKernelGGL(main_kernel,     dim3((n + 3) / 4), dim3(256), 0, stream,
                       xw, asd, offs, ssrc, batch, bias, fcw, fcb, gsumP, n);
    hipLaunchKernelGGL(final_kernel,    dim3(N_G), dim3(64), 0, stream, gsumP, a_scale, out);
}

// Round 6
// 207.325 us; speedup vs baseline: 4.3969x; 1.2063x over previous
//
#include <hip/hip_runtime.h>
#include <hip/hip_bf16.h>

typedef __hip_bfloat16 bf16;
typedef __attribute__((ext_vector_type(8))) short bf16x8;
typedef __attribute__((ext_vector_type(4))) float f32x4;

#define F_IN    128
#define HD      256
#define N_C     3
#define N_G     64
#define NEG_SLOPE 0.2f
#define NPART   512   // gsum privatization partitions

__device__ __forceinline__ float b2f(unsigned short u) {
    return __uint_as_float(((unsigned int)u) << 16);
}
// fp32 -> bf16 bits, round-nearest-even (finite inputs)
__device__ __forceinline__ unsigned short f2bs(float f) {
    unsigned int u = __float_as_uint(f);
    return (unsigned short)((u + 0x7FFFu + ((u >> 16) & 1u)) >> 16);
}

// ---------------- init: deg=1, gsumP=0, WT = bf16(W^T) ----------------
__global__ void init_kernel(int* deg, float* gsumP, const float* __restrict__ W,
                            unsigned short* __restrict__ WT, int n) {
    int i = blockIdx.x * blockDim.x + threadIdx.x;
    if (i < n) deg[i] = 1;
    if (i < N_G * N_C * NPART) gsumP[i] = 0.f;
    if (i < HD * F_IN) {
        int f = i & (F_IN - 1);
        int hd = i >> 7;
        WT[i] = f2bs(W[f * HD + hd]);
    }
}

// ---------------- count in-degrees ----------------
__global__ void count_kernel(const int* __restrict__ ei, int* deg, int e) {
    int i = blockIdx.x * blockDim.x + threadIdx.x;
    if (i < e) atomicAdd(&deg[ei[e + i]], 1);
}

// ---------------- scan phase 1: per-block exclusive scan + block totals -----
__global__ __launch_bounds__(256) void scan_blk(const int* __restrict__ deg,
                                                int* __restrict__ offs,
                                                int* __restrict__ partials, int n) {
    __shared__ int ws[4];
    int t = threadIdx.x, lane = t & 63, wid = t >> 6;
    int i = blockIdx.x * 256 + t;
    int v = (i < n) ? deg[i] : 0;
    int x = v;
    #pragma unroll
    for (int o = 1; o < 64; o <<= 1) {
        int y = __shfl_up(x, o, 64);
        if (lane >= o) x += y;
    }
    if (lane == 63) ws[wid] = x;
    __syncthreads();
    int add = 0;
    if (wid >= 1) add += ws[0];
    if (wid >= 2) add += ws[1];
    if (wid >= 3) add += ws[2];
    if (i < n) offs[i] = add + x - v;            // block-local exclusive
    if (t == 255) partials[blockIdx.x] = add + x; // block total
}

// ---------------- scan phase 2: single block scans the partials (nb<=256) ---
__global__ __launch_bounds__(256) void scan_top(int* __restrict__ partials, int nb) {
    __shared__ int ws[4];
    int t = threadIdx.x, lane = t & 63, wid = t >> 6;
    int v = (t < nb) ? partials[t] : 0;
    int x = v;
    #pragma unroll
    for (int o = 1; o < 64; o <<= 1) {
        int y = __shfl_up(x, o, 64);
        if (lane >= o) x += y;
    }
    if (lane == 63) ws[wid] = x;
    __syncthreads();
    int add = 0;
    if (wid >= 1) add += ws[0];
    if (wid >= 2) add += ws[1];
    if (wid >= 3) add += ws[2];
    if (t < nb) partials[t] = add + x - v;       // exclusive
}

// ---------------- scan phase 3: fix-up + self-loop placement + cursors ------
__global__ void scan_fix(int* __restrict__ offs, const int* __restrict__ partials,
                         int* __restrict__ ssrc, int* __restrict__ cursor,
                         int n, int tot) {
    int i = blockIdx.x * blockDim.x + threadIdx.x;
    if (i < n) {
        int o = offs[i] + partials[i >> 8];
        offs[i] = o;
        ssrc[o] = i;          // self-loop first
        cursor[i] = o + 1;
    }
    if (i == 0) offs[n] = tot;
}

// ---------------- scatter edges into CSR by target ----------------
__global__ void scatter_kernel(const int* __restrict__ ei, int* cursor,
                               int* __restrict__ ssrc, int e) {
    int i = blockIdx.x * blockDim.x + threadIdx.x;
    if (i < e) {
        int s = ei[i];
        int t = ei[e + i];
        int p = atomicAdd(&cursor[t], 1);
        ssrc[p] = s;
    }
}

// ---------------- xw = x @ W via MFMA, operand-swapped for packed stores ----
// mfma(A=WT_frag, B=x_frag): D[m=hd][n=node]; D col=lane&15 = node,
// row=quad*4+reg = hd-within-tile -> lane holds 4 CONSECUTIVE hd of one row.
// 2 row-sets (32 rows) per wave to halve WT traffic. Fused asd epilogue.
__global__ __launch_bounds__(256) void xw_mfma_kernel(const float* __restrict__ x,
                                                      const unsigned short* __restrict__ WT,
                                                      bf16* __restrict__ xw,
                                                      const float* __restrict__ att_src,
                                                      const float* __restrict__ att_dst,
                                                      float* __restrict__ asd, int n) {
    int wid = threadIdx.x >> 6, lane = threadIdx.x & 63;
    int r16 = lane & 15, quad = lane >> 4;
    int rb0 = blockIdx.x * 128 + wid * 32;
    int rb1 = rb0 + 16;
    bool v1 = rb1 < n;
    if (rb0 >= n) return;     // n % 16 == 0: rowset fully valid or fully not

    // x fragments (B operand): lane holds x[rb + r16][k = 32c + quad*8 + j]
    bf16x8 xf0[4], xf1[4];
    {
        const float* xr = x + (size_t)(rb0 + r16) * F_IN + quad * 8;
        #pragma unroll
        for (int c = 0; c < 4; c++) {
            float4 f0 = *(const float4*)(xr + c * 32);
            float4 f1 = *(const float4*)(xr + c * 32 + 4);
            bf16x8 a;
            a[0] = (short)f2bs(f0.x); a[1] = (short)f2bs(f0.y);
            a[2] = (short)f2bs(f0.z); a[3] = (short)f2bs(f0.w);
            a[4] = (short)f2bs(f1.x); a[5] = (short)f2bs(f1.y);
            a[6] = (short)f2bs(f1.z); a[7] = (short)f2bs(f1.w);
            xf0[c] = a;
        }
    }
    if (v1) {
        const float* xr = x + (size_t)(rb1 + r16) * F_IN + quad * 8;
        #pragma unroll
        for (int c = 0; c < 4; c++) {
            float4 f0 = *(const float4*)(xr + c * 32);
            float4 f1 = *(const float4*)(xr + c * 32 + 4);
            bf16x8 a;
            a[0] = (short)f2bs(f0.x); a[1] = (short)f2bs(f0.y);
            a[2] = (short)f2bs(f0.z); a[3] = (short)f2bs(f0.w);
            a[4] = (short)f2bs(f1.x); a[5] = (short)f2bs(f1.y);
            a[6] = (short)f2bs(f1.z); a[7] = (short)f2bs(f1.w);
            xf1[c] = a;
        }
    } else {
        #pragma unroll
        for (int c = 0; c < 4; c++) xf1[c] = (bf16x8)0;
    }

    // asd partials: [rowset], split by head (tiles 0-7 = head0, 8-15 = head1)
    float s0a[2] = {0,0}, s1a[2] = {0,0}, d0a[2] = {0,0}, d1a[2] = {0,0};

    const unsigned short* wtl = WT + (size_t)r16 * F_IN + quad * 8;
    for (int t = 0; t < 16; t++) {
        int colbase = t * 16;
        const unsigned short* wrow = wtl + (size_t)colbase * F_IN;
        f32x4 acc0 = {0.f,0.f,0.f,0.f}, acc1 = {0.f,0.f,0.f,0.f};
        #pragma unroll
        for (int c = 0; c < 4; c++) {
            bf16x8 wf = *(const bf16x8*)(wrow + c * 32);
            acc0 = __builtin_amdgcn_mfma_f32_16x16x32_bf16(wf, xf0[c], acc0, 0, 0, 0);
            acc1 = __builtin_amdgcn_mfma_f32_16x16x32_bf16(wf, xf1[c], acc1, 0, 0, 0);
        }
        float4 as4 = *(const float4*)(att_src + colbase + quad * 4);
        float4 ad4 = *(const float4*)(att_dst + colbase + quad * 4);

        // rowset 0: packed 8B store of 4 consecutive hd
        {
            unsigned int w0 = (unsigned int)f2bs(acc0[0]) | ((unsigned int)f2bs(acc0[1]) << 16);
            unsigned int w1 = (unsigned int)f2bs(acc0[2]) | ((unsigned int)f2bs(acc0[3]) << 16);
            *(uint2*)((unsigned short*)xw + (size_t)(rb0 + r16) * HD + colbase + quad * 4)
                = make_uint2(w0, w1);
            float ds = acc0[0]*as4.x + acc0[1]*as4.y + acc0[2]*as4.z + acc0[3]*as4.w;
            float dd = acc0[0]*ad4.x + acc0[1]*ad4.y + acc0[2]*ad4.z + acc0[3]*ad4.w;
            if (t < 8) { s0a[0] += ds; d0a[0] += dd; }
            else       { s1a[0] += ds; d1a[0] += dd; }
        }
        // rowset 1
        if (v1) {
            unsigned int w0 = (unsigned int)f2bs(acc1[0]) | ((unsigned int)f2bs(acc1[1]) << 16);
            unsigned int w1 = (unsigned int)f2bs(acc1[2]) | ((unsigned int)f2bs(acc1[3]) << 16);
            *(uint2*)((unsigned short*)xw + (size_t)(rb1 + r16) * HD + colbase + quad * 4)
                = make_uint2(w0, w1);
            float ds = acc1[0]*as4.x + acc1[1]*as4.y + acc1[2]*as4.z + acc1[3]*as4.w;
            float dd = acc1[0]*ad4.x + acc1[1]*ad4.y + acc1[2]*ad4.z + acc1[3]*ad4.w;
            if (t < 8) { s0a[1] += ds; d0a[1] += dd; }
            else       { s1a[1] += ds; d1a[1] += dd; }
        }
    }

    // reduce asd partials across quads (same node r16 lives in all 4 quads)
    #pragma unroll
    for (int o = 16; o <= 32; o <<= 1) {
        #pragma unroll
        for (int r = 0; r < 2; r++) {
            s0a[r] += __shfl_xor(s0a[r], o, 64);
            s1a[r] += __shfl_xor(s1a[r], o, 64);
            d0a[r] += __shfl_xor(d0a[r], o, 64);
            d1a[r] += __shfl_xor(d1a[r], o, 64);
        }
    }
    if (quad == 0) {
        float4 v;
        v.x = s0a[0]; v.y = s1a[0]; v.z = d0a[0]; v.w = d1a[0];
        ((float4*)asd)[rb0 + r16] = v;     // {as_h0, as_h1, ad_h0, ad_h1}
        if (v1) {
            v.x = s0a[1]; v.y = s1a[1]; v.z = d0a[1]; v.w = d1a[1];
            ((float4*)asd)[rb1 + r16] = v;
        }
    }
}

// ---------------- main: grid-stride, hoisted FC weights, lane-par softmax,
//                  MLP-4 gather, privatized pool ----------------
__global__ __launch_bounds__(256) void main_kernel(const bf16* __restrict__ xw,
                                                   const float* __restrict__ asd,
                                                   const int* __restrict__ offs,
                                                   const int* __restrict__ ssrc,
                                                   const int* __restrict__ batch,
                                                   const float* __restrict__ bias,
                                                   const float* __restrict__ fcw,
                                                   const float* __restrict__ fcb,
                                                   float* __restrict__ gsumP, int n) {
    __shared__ int   sidx[4][64];
    __shared__ float salp[4][2][64];
    int wid = threadIdx.x >> 6, lane = threadIdx.x & 63;
    int head = lane >> 5;

    // hoisted per-lane constants: bias (4), fcw rows hd..hd+3 (12 contiguous), fcb
    float4 bv = ((const float4*)bias)[lane];
    float fw[12];
    {
        const float* fp = fcw + lane * 12;
        #pragma unroll
        for (int j = 0; j < 3; j++) {
            float4 t = *(const float4*)(fp + j * 4);
            fw[j*4+0] = t.x; fw[j*4+1] = t.y; fw[j*4+2] = t.z; fw[j*4+3] = t.w;
        }
    }
    float fb0 = fcb[0], fb1 = fcb[1], fb2 = fcb[2];

    for (int node = blockIdx.x * 4 + wid; node < n; node += gridDim.x * 4) {
        float4 my = ((const float4*)asd)[node];
        float ad0 = my.z, ad1 = my.w;
        int beg = offs[node], end = offs[node + 1];
        int deg = end - beg;

        float a0 = 0.f, a1 = 0.f, a2 = 0.f, a3 = 0.f;

        if (deg <= 64) {
            bool act = lane < deg;
            int myidx = 0;
            float e0 = -1e30f, e1 = -1e30f;
            if (act) {
                myidx = ssrc[beg + lane];                    // coalesced
                float4 sa = ((const float4*)asd)[myidx];     // 64-wide gather
                e0 = sa.x + ad0; e0 = (e0 > 0.f) ? e0 : NEG_SLOPE * e0;
                e1 = sa.y + ad1; e1 = (e1 > 0.f) ? e1 : NEG_SLOPE * e1;
            }
            float m0 = e0, m1 = e1;
            #pragma unroll
            for (int o = 1; o <= 8; o <<= 1) {
                m0 = fmaxf(m0, __shfl_xor(m0, o, 64));
                m1 = fmaxf(m1, __shfl_xor(m1, o, 64));
            }
            if (deg > 16) {
                #pragma unroll
                for (int o = 16; o <= 32; o <<= 1) {
                    m0 = fmaxf(m0, __shfl_xor(m0, o, 64));
                    m1 = fmaxf(m1, __shfl_xor(m1, o, 64));
                }
            }
            float al0 = act ? __expf(e0 - m0) : 0.f;
            float al1 = act ? __expf(e1 - m1) : 0.f;
            float s0 = al0, s1 = al1;
            #pragma unroll
            for (int o = 1; o <= 8; o <<= 1) {
                s0 += __shfl_xor(s0, o, 64);
                s1 += __shfl_xor(s1, o, 64);
            }
            if (deg > 16) {
                #pragma unroll
                for (int o = 16; o <= 32; o <<= 1) {
                    s0 += __shfl_xor(s0, o, 64);
                    s1 += __shfl_xor(s1, o, 64);
                }
            }
            if (act) {
                sidx[wid][lane] = myidx;
                salp[wid][0][lane] = al0 / s0;
                salp[wid][1][lane] = al1 / s1;
            }
            // same-wave LDS write->read: in-order DS pipe, no barrier needed

            int e = 0;
            for (; e + 4 <= deg; e += 4) {
                int i0 = sidx[wid][e + 0], i1 = sidx[wid][e + 1];
                int i2 = sidx[wid][e + 2], i3 = sidx[wid][e + 3];
                ushort4 v0 = ((const ushort4*)(xw + (size_t)i0 * HD))[lane];
                ushort4 v1 = ((const ushort4*)(xw + (size_t)i1 * HD))[lane];
                ushort4 v2 = ((const ushort4*)(xw + (size_t)i2 * HD))[lane];
                ushort4 v3 = ((const ushort4*)(xw + (size_t)i3 * HD))[lane];
                float w0 = salp[wid][head][e + 0];
                float w1 = salp[wid][head][e + 1];
                float w2 = salp[wid][head][e + 2];
                float w3 = salp[wid][head][e + 3];
                a0 += w0 * b2f(v0.x) + w1 * b2f(v1.x) + w2 * b2f(v2.x) + w3 * b2f(v3.x);
                a1 += w0 * b2f(v0.y) + w1 * b2f(v1.y) + w2 * b2f(v2.y) + w3 * b2f(v3.y);
                a2 += w0 * b2f(v0.z) + w1 * b2f(v1.z) + w2 * b2f(v2.z) + w3 * b2f(v3.z);
                a3 += w0 * b2f(v0.w) + w1 * b2f(v1.w) + w2 * b2f(v2.w) + w3 * b2f(v3.w);
            }
            for (; e < deg; e++) {
                int i0 = sidx[wid][e];
                ushort4 v0 = ((const ushort4*)(xw + (size_t)i0 * HD))[lane];
                float w0 = salp[wid][head][e];
                a0 += w0 * b2f(v0.x); a1 += w0 * b2f(v0.y);
                a2 += w0 * b2f(v0.z); a3 += w0 * b2f(v0.w);
            }
        } else {
            // fallback (deg > 64, essentially never): serial two-pass
            float m0 = -1e30f, m1 = -1e30f, s0 = 0.f, s1 = 0.f;
            for (int e = beg; e < end; e++) {
                int s = ssrc[e];
                float4 sa = ((const float4*)asd)[s];
                float e0 = sa.x + ad0; e0 = (e0 > 0.f) ? e0 : NEG_SLOPE * e0;
                float e1 = sa.y + ad1; e1 = (e1 > 0.f) ? e1 : NEG_SLOPE * e1;
                float nm0 = fmaxf(m0, e0);
                s0 = s0 * __expf(m0 - nm0) + __expf(e0 - nm0); m0 = nm0;
                float nm1 = fmaxf(m1, e1);
                s1 = s1 * __expf(m1 - nm1) + __expf(e1 - nm1); m1 = nm1;
            }
            float inv0 = 1.f / s0, inv1 = 1.f / s1;
            for (int e = beg; e < end; e++) {
                int s = ssrc[e];
                float4 sa = ((const float4*)asd)[s];
                float e0 = sa.x + ad0; e0 = (e0 > 0.f) ? e0 : NEG_SLOPE * e0;
                float e1 = sa.y + ad1; e1 = (e1 > 0.f) ? e1 : NEG_SLOPE * e1;
                float al0 = __expf(e0 - m0) * inv0;
                float al1 = __expf(e1 - m1) * inv1;
                float al = (lane < 32) ? al0 : al1;
                ushort4 v = ((const ushort4*)(xw + (size_t)s * HD))[lane];
                a0 += al * b2f(v.x); a1 += al * b2f(v.y);
                a2 += al * b2f(v.z); a3 += al * b2f(v.w);
            }
        }

        // ---- epilogue: + bias, relu, FC 256->3, node log_softmax, pool ----
        float z0 = fmaxf(a0 + bv.x, 0.f);
        float z1 = fmaxf(a1 + bv.y, 0.f);
        float z2 = fmaxf(a2 + bv.z, 0.f);
        float z3 = fmaxf(a3 + bv.w, 0.f);

        float l0 = z0 * fw[0] + z1 * fw[3] + z2 * fw[6] + z3 * fw[9];
        float l1 = z0 * fw[1] + z1 * fw[4] + z2 * fw[7] + z3 * fw[10];
        float l2 = z0 * fw[2] + z1 * fw[5] + z2 * fw[8] + z3 * fw[11];
        #pragma unroll
        for (int o = 32; o > 0; o >>= 1) {
            l0 += __shfl_xor(l0, o, 64);
            l1 += __shfl_xor(l1, o, 64);
            l2 += __shfl_xor(l2, o, 64);
        }
        if (lane == 0) {
            l0 += fb0; l1 += fb1; l2 += fb2;
            float m = fmaxf(l0, fmaxf(l1, l2));
            float lse = m + __logf(__expf(l0 - m) + __expf(l1 - m) + __expf(l2 - m));
            int b = batch[node];
            int part = node & (NPART - 1);
            atomicAdd(&gsumP[(b * 3 + 0) * NPART + part], l0 - lse);
            atomicAdd(&gsumP[(b * 3 + 1) * NPART + part], l1 - lse);
            atomicAdd(&gsumP[(b * 3 + 2) * NPART + part], l2 - lse);
        }
    }
}

// ---------------- final: reduce partitions, scale by a, log_softmax --------
__global__ __launch_bounds__(64) void final_kernel(const float* __restrict__ gsumP,
                                                   const float* __restrict__ a,
                                                   float* __restrict__ out) {
    int g = blockIdx.x;        // graph id, 64 blocks
    int lane = threadIdx.x;    // 64 threads
    float v[3];
    #pragma unroll
    for (int c = 0; c < 3; c++) {
        float s = 0.f;
        for (int p = lane; p < NPART; p += 64)
            s += gsumP[(g * 3 + c) * NPART + p];
        #pragma unroll
        for (int o = 32; o > 0; o >>= 1) s += __shfl_xor(s, o, 64);
        v[c] = s;
    }
    if (lane == 0) {
        float av = a[0];
        float v0 = v[0] * av, v1 = v[1] * av, v2 = v[2] * av;
        float m = fmaxf(v0, fmaxf(v1, v2));
        float lse = m + __logf(__expf(v0 - m) + __expf(v1 - m) + __expf(v2 - m));
        out[g * 3 + 0] = v0 - lse;
        out[g * 3 + 1] = v1 - lse;
        out[g * 3 + 2] = v2 - lse;
    }
}

extern "C" void kernel_launch(void* const* d_in, const int* in_sizes, int n_in,
                              void* d_out, int out_size, void* d_ws, size_t ws_size,
                              hipStream_t stream) {
    const float* x       = (const float*)d_in[0];
    const int*   ei      = (const int*)d_in[1];
    const int*   batch   = (const int*)d_in[2];
    const float* W       = (const float*)d_in[3];
    const float* att_src = (const float*)d_in[4];
    const float* att_dst = (const float*)d_in[5];
    const float* bias    = (const float*)d_in[6];
    const float* fcw     = (const float*)d_in[7];
    const float* fcb     = (const float*)d_in[8];
    const float* a_scale = (const float*)d_in[9];
    float* out = (float*)d_out;

    const int n = in_sizes[2];       // N nodes (50000)
    const int e = in_sizes[1] / 2;   // E edges (300000)

    char* ws = (char*)d_ws;
    bf16*  xw     = (bf16*)ws;                        // N*256 bf16 = 25.6 MB
    float* asd    = (float*)(ws + 25600000);          // N*4  fp32 = 800 KB
    int*   deg    = (int*)(ws + 26400000);            // N ints (counts, then cursor)
    int*   offs   = (int*)(ws + 26600000);            // N+1 ints
    int*   ssrc   = (int*)(ws + 26800256);            // (E+N) ints
    float* gsumP  = (float*)(ws + 28200256);          // 192*512 fp32 = 393 KB
    unsigned short* WTb = (unsigned short*)(ws + 28593472);  // 256*128 bf16 = 64 KB
    int*   partials = (int*)(ws + 28659008);          // scan block partials

    int nb256 = (n + 255) / 256;                      // 196
    int eb256 = (e + 255) / 256;
    int ib256 = (N_G * N_C * NPART + 255) / 256;      // init covers gsumP + WT + deg
    if (ib256 < nb256) ib256 = nb256;

    hipLaunchKernelGGL(init_kernel,    dim3(ib256), dim3(256), 0, stream, deg, gsumP, W, WTb, n);
    hipLaunchKernelGGL(count_kernel,   dim3(eb256), dim3(256), 0, stream, ei, deg, e);
    hipLaunchKernelGGL(scan_blk,       dim3(nb256), dim3(256), 0, stream, deg, offs, partials, n);
    hipLaunchKernelGGL(scan_top,       dim3(1), dim3(256), 0, stream, partials, nb256);
    hipLaunchKernelGGL(scan_fix,       dim3(nb256), dim3(256), 0, stream, offs, partials, ssrc, deg, n, n + e);
    hipLaunchKernelGGL(scatter_kernel, dim3(eb256), dim3(256), 0, stream, ei, deg, ssrc, e);
    hipLaunchKernelGGL(xw_mfma_kernel, dim3((n + 127) / 128), dim3(256), 0, stream,
                       x, WTb, xw, att_src, att_dst, asd, n);
    hipLaunchKernelGGL(main_kernel,    dim3(2048), dim3(256), 0, stream,
                       xw, asd, offs, ssrc, batch, bias, fcw, fcb, gsumP, n);
    hipLaunchKernelGGL(final_kernel,   dim3(N_G), dim3(64), 0, stream, gsumP, a_scale, out);
}